// Round 2
// baseline (354.886 us; speedup 1.0000x reference)
//
#include <hip/hip_runtime.h>

// gConv3d separable factorization:
//   q[n,o,b,h,w]   = sum_{c,f} x[c, n+f, h, w] * weight[o,c,f,b]        (K=216)
//   s[n,g,o,ii,jj] = sum_{b,u,v} q[n,o,b,ii+u,jj+v] * basis[g][(b,u,v)] (K=63)
//   out[g*8+o, xo+1,yo+1,zo+1, h, w] = s[n, T(g,h,w), o, clip(h)-1, clip(w)-1] + bias_sum[o]
// T(g,h,w) = (g+1)%12 on the (h,w) border, else g. Non-interior xyz = 0.
//
// R6 changes vs R5 (R5 null result proved LDS was never the bottleneck:
// removing 756 broadcast reads/wave changed nothing, bank-conflict counter
// bit-identical -> conflicts are the qw stencil reads. Kernel is stage-1
// latency-bound: per c-iter each wave drains 378 weight floats through
// SGPR-chunked s_loads (SMEM is OoO -> every chunk is a full lgkmcnt(0))
// plus one vmcnt wait for 27 x loads, vs only ~756 cyc of FMA issue):
//  - NZ=3, OG=1: each block computes 3 consecutive zo for ONE o.
//    * each weight float feeds 3 FMAs (was 1) -> SMEM stalls per FMA /3
//    * x taps overlap: 45 loads/c-iter serve 3 n (was 27 per n) -> 1.8x
//      fewer vector loads per FMA
//    * 243 triples x 8 o = 1944 blocks exactly (=8*243, no pad, clean XCD
//      split, tail 1.27 rounds vs 1.9)
//  - acc = 21 regs -> __launch_bounds__(320,8) (VGPR<=64) keeps 6 blocks/CU.
//  - qs holds all 3 n (26880 B, 6 blocks still fit LDS) -> single barrier;
//    stage-2 dz-outer to keep VGPR low.
// Total FMA unchanged (4.23G, 54 us floor). Target ~115-135 us/dispatch.

#define HW 320
#define NZ 3
#define NPAD 1944     // 243 n-triples * 8 o, divisible by 8

__global__ __launch_bounds__(320, 8) void fused_kernel(
    const float* __restrict__ x, const float* __restrict__ weight,
    const float* __restrict__ bias, const float* __restrict__ basis,
    float* __restrict__ out)
{
    __shared__ float qs[NZ * 7 * HW];   // 26880 B

    const int tid = threadIdx.x;

    // ---- border zero-fill (grid-strided, masked, coalesced) ----
    {
        float4* out4 = (float4*)out;
        const float4 z = make_float4(0.f, 0.f, 0.f, 0.f);
        for (int s = blockIdx.x * 320 + tid; s < 96 * 1728 * 80; s += NPAD * 320) {
            int row = s / 80;                      // go*1728 + xyz
            int xyz = row - (row / 1728) * 1728;
            int xi = xyz / 144;
            int r2 = xyz - xi * 144;
            int yi = r2 / 12;
            int zi = r2 - yi * 12;
            if (!((unsigned)(xi - 1) < 9u && (unsigned)(yi - 1) < 9u &&
                  (unsigned)(zi - 1) < 9u))
                out4[s] = z;
        }
    }

    // XCD-aware swizzle: contiguous logical range per XCD. The 8 o-blocks of
    // one n-triple are consecutive logicals -> same XCD (share all x taps).
    const int xcd  = blockIdx.x & 7;
    const int slot = blockIdx.x >> 3;
    const int logical = xcd * (NPAD / 8) + slot;   // 0..1943, no padding

    const int ntri = logical >> 3;                 // 0..242
    const int o0   = logical & 7;
    const int xo = ntri / 27;
    const int rem = ntri - xo * 27;
    const int yo = rem / 3;
    const int zo = (rem - yo * 3) * NZ;            // 0, 3, 6

    // ---------------- stage 1: q for 3 zo into registers ----------------
    float acc[NZ * 7];
    #pragma unroll
    for (int i = 0; i < NZ * 7; ++i) acc[i] = 0.f;

    const float* xb = x + ((xo * 12 + yo) * 12 + zo) * HW + tid;

    #pragma unroll 1
    for (int c = 0; c < 8; ++c) {
        const float* xc = xb + c * 1728 * HW;
        const float* wc = weight + o0 * 1512 + c * 189;   // uniform -> s_load
        #pragma unroll
        for (int fi = 0; fi < 3; ++fi) {
            #pragma unroll
            for (int fj = 0; fj < 3; ++fj) {
                // 5 x taps cover fk=0..2 for dz=0..2
                float xv[NZ + 2];
                #pragma unroll
                for (int k5 = 0; k5 < NZ + 2; ++k5)
                    xv[k5] = xc[(fi * 144 + fj * 12 + k5) * HW];
                #pragma unroll
                for (int fk = 0; fk < 3; ++fk) {
                    const float* wp = wc + fi * 63 + fj * 21 + fk * 7;
                    #pragma unroll
                    for (int b = 0; b < 7; ++b) {
                        const float wv = wp[b];    // each weight feeds 3 FMAs
                        #pragma unroll
                        for (int dz = 0; dz < NZ; ++dz)
                            acc[dz * 7 + b] = fmaf(xv[dz + fk], wv, acc[dz * 7 + b]);
                    }
                }
            }
        }
    }

    #pragma unroll
    for (int i = 0; i < NZ * 7; ++i) qs[i * HW + tid] = acc[i];
    __syncthreads();

    // ---------------- stage 2: dz-outer, basis via scalar loads ----------------
    const int h = tid / 40;
    const int w = tid - h * 40;
    const int ii = min(max(h, 1), 6) - 1;    // 0..5
    const int jj = min(max(w, 1), 38) - 1;   // 0..37
    const bool border = (h == 0) | (h == 7) | (w == 0) | (w == 39);
    const int base_hw = ii * 40 + jj;

    // bias sum (wave-uniform s_loads)
    float bs = 0.f;
    #pragma unroll
    for (int i = 0; i < 27; ++i) bs += bias[o0 * 27 + i];

    #pragma unroll 1
    for (int dz = 0; dz < NZ; ++dz) {
        float s[12];
        #pragma unroll
        for (int g = 0; g < 12; ++g) s[g] = 0.f;

        #pragma unroll 1
        for (int b = 0; b < 7; ++b) {
            float qw[9];
            #pragma unroll
            for (int uv = 0; uv < 9; ++uv) {
                const int u = uv / 3, v = uv - (uv / 3) * 3;
                qw[uv] = qs[(dz * 7 + b) * HW + base_hw + u * 40 + v];
            }
            const float* bb = basis + b * 9;
            #pragma unroll
            for (int g = 0; g < 12; ++g)
                #pragma unroll
                for (int uv = 0; uv < 9; ++uv)
                    s[g] = fmaf(qw[uv], bb[g * 63 + uv], s[g]);  // uniform s_load
        }

        const int out_xyz = ((xo + 1) * 144 + (yo + 1) * 12 + (zo + dz + 1)) * HW + tid;
        #pragma unroll
        for (int g = 0; g < 12; ++g) {
            float val = (border ? s[(g + 1) % 12] : s[g]) + bs;
            out[(g * 8 + o0) * (1728 * HW) + out_xyz] = val;
        }
    }
}

extern "C" void kernel_launch(void* const* d_in, const int* in_sizes, int n_in,
                              void* d_out, int out_size, void* d_ws, size_t ws_size,
                              hipStream_t stream)
{
    const float* x      = (const float*)d_in[0];
    const float* weight = (const float*)d_in[1];
    const float* bias   = (const float*)d_in[2];
    const float* basis  = (const float*)d_in[3];
    float* out = (float*)d_out;

    fused_kernel<<<NPAD, 320, 0, stream>>>(x, weight, bias, basis, out);
}

// Round 3
// 331.395 us; speedup vs baseline: 1.0709x; 1.0709x over previous
//
#include <hip/hip_runtime.h>

// gConv3d separable factorization:
//   q[n,o,b,h,w]   = sum_{c,f} x[c, n+f, h, w] * weight[o,c,f,b]        (K=216)
//   s[n,g,o,ii,jj] = sum_{b,u,v} q[n,o,b,ii+u,jj+v] * basis[g][(b,u,v)] (K=63)
//   out[g*8+o, xo+1,yo+1,zo+1, h, w] = s[n, T(g,h,w), o, clip(h)-1, clip(w)-1] + bias_sum[o]
// T(g,h,w) = (g+1)%12 on the (h,w) border, else g. Non-interior xyz = 0.
//
// R7 changes vs R6 (R6 regressed from SCRATCH SPILL, not from the NZ=3 idea:
// WRITE_SIZE 207360 KB [exactly the output] -> 300549 KB (+93 MB) with
// identical store footprint, under launch_bounds(320,8)'s 64-VGPR cap.
// VALU busy-time is invariant ~80-85 us across R4-R6; dur = VALU/VALUBusy):
//  - launch_bounds back to (320,7): 72-VGPR cap (R5's known spill-free
//    setting). Stage-1 live set ~50-60 regs fits.
//  - zero-fill incremental decode: stride 622080 float4 = 7776 rows, and
//    7776 mod 1728 = 864 = 6*144 -> (yi,zi) per-thread INVARIANT, xi
//    alternates between xi0 and (xi0+6)%12. Decode once, two masks,
//    ~2 inst/iter instead of a ~40-inst div chain.
//  - everything else = R6: NZ=3 weight reuse (each s_load float feeds 3
//    FMAs -> SMEM-wait per FMA /3), 45 x-loads serve 3 n per c-iter,
//    1944 = 8*243 blocks, single barrier, dz-outer stage 2.
// Floors: FMA 54 us, VALU total ~75 us, HBM write 34 us. Target 110-135 us.

#define HW 320
#define NZ 3
#define NPAD 1944     // 243 n-triples * 8 o, divisible by 8

__global__ __launch_bounds__(320, 7) void fused_kernel(
    const float* __restrict__ x, const float* __restrict__ weight,
    const float* __restrict__ bias, const float* __restrict__ basis,
    float* __restrict__ out)
{
    __shared__ float qs[NZ * 7 * HW];   // 26880 B

    const int tid = threadIdx.x;

    // ---- border zero-fill (grid-strided; incremental row decode) ----
    {
        float4* out4 = (float4*)out;
        const float4 z = make_float4(0.f, 0.f, 0.f, 0.f);
        int s = blockIdx.x * 320 + tid;
        // decode ONCE: row advances 7776/iter; 7776 % 1728 = 864 = 6*144,
        // so (yi,zi) never change and xi alternates xi0 <-> (xi0+6)%12.
        int row = s / 80;
        int xyz = row - (row / 1728) * 1728;
        int xi = xyz / 144;
        int r2 = xyz - xi * 144;
        int yi = r2 / 12;
        int zi = r2 - yi * 12;
        int xi2 = xi + 6; if (xi2 >= 12) xi2 -= 12;
        const bool yzok = ((unsigned)(yi - 1) < 9u) & ((unsigned)(zi - 1) < 9u);
        const bool bE = !(yzok & ((unsigned)(xi  - 1) < 9u));
        const bool bO = !(yzok & ((unsigned)(xi2 - 1) < 9u));
        #pragma unroll 1
        for (int k = 0; s < 96 * 1728 * 80; s += NPAD * 320, ++k) {
            if ((k & 1) ? bO : bE) out4[s] = z;
        }
    }

    // XCD-aware swizzle: contiguous logical range per XCD. The 8 o-blocks of
    // one n-triple are consecutive logicals -> same XCD (share all x taps).
    const int xcd  = blockIdx.x & 7;
    const int slot = blockIdx.x >> 3;
    const int logical = xcd * (NPAD / 8) + slot;   // 0..1943, no padding

    const int ntri = logical >> 3;                 // 0..242
    const int o0   = logical & 7;
    const int xo = ntri / 27;
    const int rem = ntri - xo * 27;
    const int yo = rem / 3;
    const int zo = (rem - yo * 3) * NZ;            // 0, 3, 6

    // ---------------- stage 1: q for 3 zo into registers ----------------
    float acc[NZ * 7];
    #pragma unroll
    for (int i = 0; i < NZ * 7; ++i) acc[i] = 0.f;

    const float* xb = x + ((xo * 12 + yo) * 12 + zo) * HW + tid;

    #pragma unroll 1
    for (int c = 0; c < 8; ++c) {
        const float* xc = xb + c * 1728 * HW;
        const float* wc = weight + o0 * 1512 + c * 189;   // uniform -> s_load
        #pragma unroll
        for (int fi = 0; fi < 3; ++fi) {
            #pragma unroll
            for (int fj = 0; fj < 3; ++fj) {
                // 5 x taps cover fk=0..2 for dz=0..2
                float xv[NZ + 2];
                #pragma unroll
                for (int k5 = 0; k5 < NZ + 2; ++k5)
                    xv[k5] = xc[(fi * 144 + fj * 12 + k5) * HW];
                #pragma unroll
                for (int fk = 0; fk < 3; ++fk) {
                    const float* wp = wc + fi * 63 + fj * 21 + fk * 7;
                    #pragma unroll
                    for (int b = 0; b < 7; ++b) {
                        const float wv = wp[b];    // each weight feeds 3 FMAs
                        #pragma unroll
                        for (int dz = 0; dz < NZ; ++dz)
                            acc[dz * 7 + b] = fmaf(xv[dz + fk], wv, acc[dz * 7 + b]);
                    }
                }
            }
        }
    }

    #pragma unroll
    for (int i = 0; i < NZ * 7; ++i) qs[i * HW + tid] = acc[i];
    __syncthreads();

    // ---------------- stage 2: dz-outer, basis via scalar loads ----------------
    const int h = tid / 40;
    const int w = tid - h * 40;
    const int ii = min(max(h, 1), 6) - 1;    // 0..5
    const int jj = min(max(w, 1), 38) - 1;   // 0..37
    const bool border = (h == 0) | (h == 7) | (w == 0) | (w == 39);
    const int base_hw = ii * 40 + jj;

    // bias sum (wave-uniform s_loads)
    float bs = 0.f;
    #pragma unroll
    for (int i = 0; i < 27; ++i) bs += bias[o0 * 27 + i];

    #pragma unroll 1
    for (int dz = 0; dz < NZ; ++dz) {
        float s[12];
        #pragma unroll
        for (int g = 0; g < 12; ++g) s[g] = 0.f;

        #pragma unroll 1
        for (int b = 0; b < 7; ++b) {
            float qw[9];
            #pragma unroll
            for (int uv = 0; uv < 9; ++uv) {
                const int u = uv / 3, v = uv - (uv / 3) * 3;
                qw[uv] = qs[(dz * 7 + b) * HW + base_hw + u * 40 + v];
            }
            const float* bb = basis + b * 9;
            #pragma unroll
            for (int g = 0; g < 12; ++g)
                #pragma unroll
                for (int uv = 0; uv < 9; ++uv)
                    s[g] = fmaf(qw[uv], bb[g * 63 + uv], s[g]);  // uniform s_load
        }

        const int out_xyz = ((xo + 1) * 144 + (yo + 1) * 12 + (zo + dz + 1)) * HW + tid;
        #pragma unroll
        for (int g = 0; g < 12; ++g) {
            float val = (border ? s[(g + 1) % 12] : s[g]) + bs;
            out[(g * 8 + o0) * (1728 * HW) + out_xyz] = val;
        }
    }
}

extern "C" void kernel_launch(void* const* d_in, const int* in_sizes, int n_in,
                              void* d_out, int out_size, void* d_ws, size_t ws_size,
                              hipStream_t stream)
{
    const float* x      = (const float*)d_in[0];
    const float* weight = (const float*)d_in[1];
    const float* bias   = (const float*)d_in[2];
    const float* basis  = (const float*)d_in[3];
    float* out = (float*)d_out;

    fused_kernel<<<NPAD, 320, 0, stream>>>(x, weight, bias, basis, out);
}